// Round 10
// baseline (5280.291 us; speedup 1.0000x reference)
//
#include <hip/hip_runtime.h>

typedef short short8 __attribute__((ext_vector_type(8)));
typedef float f32x4 __attribute__((ext_vector_type(4)));
typedef float f32x16 __attribute__((ext_vector_type(16)));
typedef int i32x4 __attribute__((ext_vector_type(4)));
typedef unsigned short u16;
typedef unsigned long long u64;

#define NBLK 256
#define BDIM 512
#define BB 64
#define TT 512
#define II 512
#define HH 1024
#define NCLS 1000
#define HBUF (BB*HH)

__device__ __forceinline__ u16 f2bf(float f) {
  union { float f; unsigned u; } v; v.f = f;
  unsigned u = v.u;
  u += 0x7fffu + ((u >> 16) & 1u);   // RNE
  return (u16)(u >> 16);
}

__device__ __forceinline__ short8 cvt8(f32x4 a, f32x4 b) {
  short8 v;
  v[0] = (short)f2bf(a[0]); v[1] = (short)f2bf(a[1]);
  v[2] = (short)f2bf(a[2]); v[3] = (short)f2bf(a[3]);
  v[4] = (short)f2bf(b[0]); v[5] = (short)f2bf(b[1]);
  v[6] = (short)f2bf(b[2]); v[7] = (short)f2bf(b[3]);
  return v;
}

__device__ __forceinline__ unsigned ld_rlx(const unsigned* p) {
  return __hip_atomic_load(p, __ATOMIC_RELAXED, __HIP_MEMORY_SCOPE_AGENT);
}
__device__ __forceinline__ void st_rlx(unsigned* p, unsigned v) {
  __hip_atomic_store(p, v, __ATOMIC_RELAXED, __HIP_MEMORY_SCOPE_AGENT);
}
// wave-wide wait on 8 group flags (stride 32 u32 = 128B lines): lanes 0-7 each
// poll one flag; done when ALL flags >= tgt. One load round = 8 parallel LLC reqs.
__device__ __forceinline__ void wave_wait_all8(const unsigned* base, unsigned tgt,
                                               int lane) {
  const unsigned* p = base + (unsigned)(lane & 7) * 32;
  for (;;) {
    unsigned v = ld_rlx(p);
    if (__all((int)(v >= tgt))) break;
    __builtin_amdgcn_s_sleep(1);
  }
}

// x f32 -> bf16 pre-pass (tier A)
__global__ void cvt_x(const float* __restrict__ x, u16* __restrict__ xb, int n8) {
  int i = blockIdx.x * blockDim.x + threadIdx.x;
  const int stride = gridDim.x * blockDim.x;
  for (; i < n8; i += stride) {
    f32x4 a = ((const f32x4*)x)[2 * i];
    f32x4 b = ((const f32x4*)x)[2 * i + 1];
    ((short8*)xb)[i] = cvt8(a, b);
  }
}

// ---- coherent fragment run: 2-deep pipelined batches, counted vmcnt ----
#define ISSUE8(arr, OFF)                                                     \
  _Pragma("unroll") for (int i_ = 0; i_ < 8; ++i_)                           \
    asm volatile("global_load_dwordx4 %0, %1, off sc0 sc1"                   \
                 : "=v"(arr[i_]) : "v"(lanep + ((OFF) + i_) * 16));
#define MFMA8(arr, OFF)                                                      \
  _Pragma("unroll") for (int i_ = 0; i_ < 8; ++i_) {                         \
    union { i32x4 q; short8 s; } u_; u_.q = arr[i_];                         \
    acc = __builtin_amdgcn_mfma_f32_32x32x16_bf16(u_.s, breg[B0 + (OFF) + i_],\
                                                  acc, 0, 0, 0); }
#define VMWAIT0 asm volatile("s_waitcnt vmcnt(0)" ::: "memory")
#define VMWAIT8 asm volatile("s_waitcnt vmcnt(8)" ::: "memory")
#define SCHEDB  __builtin_amdgcn_sched_barrier(0)

template<int N, int B0, int MH>
__device__ __forceinline__ void run_coh(const u16* lanep,
                                        const short8 (&breg)[MH], f32x16& acc) {
  static_assert(N == 8 || N == 16 || N == 24 || N == 32, "");
  i32x4 avA[8], avB[8];
  if constexpr (N == 8) {
    ISSUE8(avA, 0);
    VMWAIT0; SCHEDB; MFMA8(avA, 0);
  } else if constexpr (N == 16) {
    ISSUE8(avA, 0); ISSUE8(avB, 8);
    VMWAIT8; SCHEDB; MFMA8(avA, 0);
    VMWAIT0; SCHEDB; MFMA8(avB, 8);
  } else if constexpr (N == 24) {
    ISSUE8(avA, 0); ISSUE8(avB, 8);
    VMWAIT8; SCHEDB; MFMA8(avA, 0); ISSUE8(avA, 16);
    VMWAIT8; SCHEDB; MFMA8(avB, 8);
    VMWAIT0; SCHEDB; MFMA8(avA, 16);
  } else {
    ISSUE8(avA, 0); ISSUE8(avB, 8);
    VMWAIT8; SCHEDB; MFMA8(avA, 0); ISSUE8(avA, 16);
    VMWAIT8; SCHEDB; MFMA8(avB, 8); ISSUE8(avB, 24);
    VMWAIT8; SCHEDB; MFMA8(avA, 16);
    VMWAIT0; SCHEDB; MFMA8(avB, 24);
  }
}

// plain cached bf16 run (L0 x-section, tier A)
template<int N, int B0, int MH>
__device__ __forceinline__ void run_pb(const u16* lanep,
                                       const short8 (&breg)[MH], f32x16& acc) {
#pragma unroll
  for (int i = 0; i < N; ++i) {
    short8 av = *(const short8*)(lanep + i * 16);
    acc = __builtin_amdgcn_mfma_f32_32x32x16_bf16(av, breg[B0 + i], acc, 0, 0, 0);
  }
}

// plain cached f32 run + convert (L0 x-section, tier B)
template<int N, int B0, int MH>
__device__ __forceinline__ void run_pf(const float* lanep,
                                       const short8 (&breg)[MH], f32x16& acc) {
#pragma unroll
  for (int i = 0; i < N; ++i) {
    short8 av = cvt8(*(const f32x4*)(lanep + i * 16),
                     *(const f32x4*)(lanep + i * 16 + 4));
    acc = __builtin_amdgcn_mfma_f32_32x32x16_bf16(av, breg[B0 + i], acc, 0, 0, 0);
  }
}

// Decoupled persistent 2-layer LSTM, grouped-barrier edition.
// Blocks [0,128)=L0, [128,256)=L1; 8 waves = 2 M-halves x 4 K-quarters;
// weights in registers (32x32x16 MFMA). Arrive: 8 group counters of 16 blocks
// (separate 128B lines); 16th arriver posts its group release flag directly.
// Consumers wait with a wave-wide 8-flag poll (no root hop, 16 RMWs/line max).
template<bool XBF>
__global__ __launch_bounds__(BDIM, 2) void lstm2_fused(
    const float* __restrict__ x, const u16* __restrict__ xb,
    const float* __restrict__ Wih0, const float* __restrict__ Whh0,
    const float* __restrict__ bih0, const float* __restrict__ bhh0,
    const float* __restrict__ Wih1, const float* __restrict__ Whh1,
    const float* __restrict__ bih1, const float* __restrict__ bhh1,
    u16* __restrict__ ring,          // 3 x [64][1024] bf16 (h0)
    u16* __restrict__ h1buf,         // 2 x [64][1024] bf16 (h1)
    float* __restrict__ h1f,
    unsigned* __restrict__ bar)
{
  __shared__ u16 wlds[32 * 2048];        // 128 KB weight staging (prologue only)
  __shared__ float blds[32];             // fused biases
  float (*g4)[64][32] = (float(*)[64][32])((char*)wlds + 98304);  // aliased 32 KB

  const bool isL1 = (blockIdx.x >= 128);
  const int wgl = isL1 ? (int)blockIdx.x - 128 : (int)blockIdx.x;
  const int j0 = wgl * 8;
  const int grp = wgl >> 4;              // barrier group (16 blocks each)
  const int KX = isL1 ? HH : II;
  const int RL = KX + HH;                // 2048 / 1536
  const int ROWB = RL * 2;
  const float* Wih = isL1 ? Wih1 : Wih0;
  const float* Whh = isL1 ? Whh1 : Whh0;

  // ---- stage weights into LDS (f32 -> bf16), swizzle byte ^= (row&7)<<4 ----
  {
    const int cpr = RL / 8;
    for (int idx = threadIdx.x; idx < 32 * cpr; idx += BDIM) {
      int n = idx / cpr, cb = idx - n * cpr;
      int r = ((n >> 3) << 10) + j0 + (n & 7);
      int k = cb * 8;
      const float* src = (k < KX) ? (Wih + (size_t)r * KX + k)
                                  : (Whh + (size_t)r * HH + (k - KX));
      f32x4 a = *(const f32x4*)src;
      f32x4 b = *(const f32x4*)(src + 4);
      short8 v = cvt8(a, b);
      unsigned byte = (unsigned)(n * ROWB + k * 2) ^ ((unsigned)(n & 7) << 4);
      *(short8*)((char*)wlds + byte) = v;
    }
    if (threadIdx.x < 32) {
      int n = threadIdx.x;
      int r = ((n >> 3) << 10) + j0 + (n & 7);
      blds[n] = (isL1 ? bih1[r] : bih0[r]) + (isL1 ? bhh1[r] : bhh0[r]);
    }
  }
  __syncthreads();

  const int lane = threadIdx.x & 63;
  const int wid = threadIdx.x >> 6;
  const int mp = wid & 1, kq = wid >> 1; // 2 M-halves x 4 K-quarters
  const int row_a = mp * 32 + (lane & 31);
  const int sub8 = (lane >> 5) << 3;
  const char* wch = (const char*)wlds;

  const int tb = threadIdx.x >> 3, tj = threadIdx.x & 7;

  // flag arrays: 8 entries each, stride 32 u32 (128B lines)
  unsigned* const arrA = bar;            // L0 group arrive counters
  unsigned* const relA = bar + 256;      // L0 group release flags
  unsigned* const arrB = bar + 512;      // L1 group arrive counters
  unsigned* const relB = bar + 768;      // L1 group release flags

  float c_state = 0.f;

  // tail: K-partial combine, gates, c/h update, coherent h store, group arrive.
  auto step_tail = [&](const f32x16& acc, u16* hout, unsigned ringtgt, bool wf,
                       unsigned* arr, unsigned* rel, int t) {
    const int col = lane & 31;
    const int rbase = mp * 32 + ((lane >> 5) << 2);
#pragma unroll
    for (int r = 0; r < 16; ++r) {
      int brow = rbase + (r & 3) + ((r >> 2) << 3);
      g4[kq][brow][col] = acc[r];
    }
    __syncthreads();
    float gv[4];
#pragma unroll
    for (int g = 0; g < 4; ++g)
      gv[g] = g4[0][tb][g * 8 + tj] + g4[1][tb][g * 8 + tj]
            + g4[2][tb][g * 8 + tj] + g4[3][tb][g * 8 + tj] + blds[g * 8 + tj];
    float gi = 1.f / (1.f + __expf(-gv[0]));
    float gf = 1.f / (1.f + __expf(-gv[1]));
    float e2 = __expf(2.f * fminf(15.f, fmaxf(-15.f, gv[2])));
    float gg = (e2 - 1.f) / (e2 + 1.f);
    float go = 1.f / (1.f + __expf(-gv[3]));
    c_state = gf * c_state + gi * gg;
    float e2c = __expf(2.f * fminf(15.f, fmaxf(-15.f, c_state)));
    float th = (e2c - 1.f) / (e2c + 1.f);
    float hval = go * th;
    if (ringtgt) wave_wait_all8(relB, ringtgt, lane);  // L0 ring reuse guard
    unsigned hu = (unsigned)f2bf(hval);
    unsigned nbv = (unsigned)__shfl_xor((int)hu, 1);
    if ((tj & 1) == 0) {
      unsigned packed = hu | (nbv << 16);
      unsigned* dst = (unsigned*)(hout + (size_t)tb * HH + j0 + tj);
      st_rlx(dst, packed);
    }
    if (wf) h1f[(size_t)tb * HH + j0 + tj] = hval;
    __syncthreads();                    // drains h stores (vmcnt) wave-by-wave
    if (threadIdx.x == 0) {             // group arrive; 16th poster releases grp
      unsigned old = atomicAdd(arr + grp * 32, 1u);
      if (old == (unsigned)(16 * (t + 1) - 1))
        st_rlx(rel + grp * 32, (unsigned)(t + 1));
    }
  };

  if (!isL1) {
    // ================= layer 0: 24 frags/wave; x-section needs no flag =======
    short8 breg[24];
#pragma unroll
    for (int i = 0; i < 24; ++i) {
      int k = (kq * 24 + i) * 16 + sub8;
      unsigned byte = ((unsigned)((lane & 31) * ROWB + k * 2))
                      ^ ((unsigned)(lane & 7) << 4);
      breg[i] = *(const short8*)(wch + byte);
    }
    __syncthreads();                     // breg reads done before g4 aliasing

    for (int t = 0; t < TT; ++t) {
      f32x16 acc = {};
      const u16* hb = ring + (size_t)((t + 2) % 3) * HBUF + (size_t)row_a * HH;
      if (XBF) {
        const u16* xl = xb + (size_t)t * II + (size_t)row_a * ((size_t)TT * II)
                        + kq * 384 + sub8;
        if (kq == 0)      run_pb<24, 0>(xl, breg, acc);
        else if (kq == 1) { run_pb<8, 0>(xl, breg, acc);
                            wave_wait_all8(relA, (unsigned)t, lane);
                            run_coh<16, 8>(hb + 0 + sub8, breg, acc); }
        else if (kq == 2) { wave_wait_all8(relA, (unsigned)t, lane);
                            run_coh<24, 0>(hb + 256 + sub8, breg, acc); }
        else              { wave_wait_all8(relA, (unsigned)t, lane);
                            run_coh<24, 0>(hb + 640 + sub8, breg, acc); }
      } else {
        const float* xl = x + (size_t)t * II + (size_t)row_a * ((size_t)TT * II)
                          + kq * 384 + sub8;
        if (kq == 0)      run_pf<24, 0>(xl, breg, acc);
        else if (kq == 1) { run_pf<8, 0>(xl, breg, acc);
                            wave_wait_all8(relA, (unsigned)t, lane);
                            run_coh<16, 8>(hb + 0 + sub8, breg, acc); }
        else if (kq == 2) { wave_wait_all8(relA, (unsigned)t, lane);
                            run_coh<24, 0>(hb + 256 + sub8, breg, acc); }
        else              { wave_wait_all8(relA, (unsigned)t, lane);
                            run_coh<24, 0>(hb + 640 + sub8, breg, acc); }
      }
      step_tail(acc, ring + (size_t)(t % 3) * HBUF,
                (t >= 3) ? (unsigned)(t - 2) : 0u, false, arrA, relA, t);
    }
  } else {
    // ================= layer 1: 32 frags/wave; input half waits only on relA ==
    short8 breg[32];
#pragma unroll
    for (int i = 0; i < 32; ++i) {
      int k = (kq * 32 + i) * 16 + sub8;
      unsigned byte = ((unsigned)((lane & 31) * ROWB + k * 2))
                      ^ ((unsigned)(lane & 7) << 4);
      breg[i] = *(const short8*)(wch + byte);
    }
    __syncthreads();                     // breg reads done before g4 aliasing

    for (int t = 0; t < TT; ++t) {
      f32x16 acc = {};
      if (kq < 2) {                      // input: h0(t) = ring slot t%3
        wave_wait_all8(relA, (unsigned)(t + 1), lane);
        const u16* lp = ring + (size_t)(t % 3) * HBUF + (size_t)row_a * HH
                        + kq * 512 + sub8;
        run_coh<32, 0>(lp, breg, acc);
      } else {                           // recurrent: h1(t-1)
        wave_wait_all8(relB, (unsigned)t, lane);
        const u16* lp = h1buf + (size_t)((t + 1) & 1) * HBUF
                        + (size_t)row_a * HH + (kq - 2) * 512 + sub8;
        run_coh<32, 0>(lp, breg, acc);
      }
      step_tail(acc, h1buf + (size_t)(t & 1) * HBUF, 0u, t == TT - 1,
                arrB, relB, t);
    }
  }
}

// out[b][c] = sum_k h1f[b][k] * Wd[c][k] + bd[c]   (all f32)
__global__ void dense_out(const float* __restrict__ h1, const float* __restrict__ Wd,
                          const float* __restrict__ bd, float* __restrict__ out)
{
  const int b  = threadIdx.x & 63;
  const int cl = threadIdx.x >> 6;
  const int cc = blockIdx.x * 4 + cl;    // class (250*4 = 1000)
  float acc = 0.f;
  const float* hrow = h1 + (size_t)b * HH;
  const float* wrow = Wd + (size_t)cc * HH;
#pragma unroll 8
  for (int k = 0; k < HH; k += 4) {
    f32x4 hv = *(const f32x4*)(hrow + k);
    f32x4 wv = *(const f32x4*)(wrow + k);
    acc += hv[0] * wv[0] + hv[1] * wv[1] + hv[2] * wv[2] + hv[3] * wv[3];
  }
  out[(size_t)b * NCLS + cc] = acc + bd[cc];
}

extern "C" void kernel_launch(void* const* d_in, const int* in_sizes, int n_in,
                              void* d_out, int out_size, void* d_ws, size_t ws_size,
                              hipStream_t stream)
{
  (void)in_sizes; (void)n_in; (void)out_size;
  const float* x    = (const float*)d_in[0];
  const float* Wih0 = (const float*)d_in[1];
  const float* Whh0 = (const float*)d_in[2];
  const float* bih0 = (const float*)d_in[3];
  const float* bhh0 = (const float*)d_in[4];
  const float* Wih1 = (const float*)d_in[5];
  const float* Whh1 = (const float*)d_in[6];
  const float* bih1 = (const float*)d_in[7];
  const float* bhh1 = (const float*)d_in[8];
  const float* Wd   = (const float*)d_in[9];
  const float* bd   = (const float*)d_in[10];

  unsigned* bar = (unsigned*)d_ws;                       // 4 KB flag/counter lines
  float* h1f  = (float*)((char*)d_ws + 4096);            // 256 KB
  u16* h1buf  = (u16*)((char*)d_ws + 272 * 1024);        // 2 x 128 KB
  u16* ring   = (u16*)((char*)d_ws + 528 * 1024);        // 3 x 128 KB
  u16* xb     = (u16*)((char*)d_ws + (1u << 20));        // 33.6 MB (tier A)

  const size_t needA = (1u << 20) + (size_t)BB * TT * II * 2;
  const bool tierA = (ws_size >= needA);

  // zero flags + h buffers every launch (graph-replay deterministic)
  hipMemsetAsync(d_ws, 0, 912 * 1024, stream);

  if (tierA) {
    hipLaunchKernelGGL(cvt_x, dim3(2048), dim3(256), 0, stream,
                       x, xb, (int)((size_t)BB * TT * II / 8));
    hipLaunchKernelGGL((lstm2_fused<true>), dim3(NBLK), dim3(BDIM), 0, stream,
                       x, xb, Wih0, Whh0, bih0, bhh0, Wih1, Whh1, bih1, bhh1,
                       ring, h1buf, h1f, bar);
  } else {
    hipLaunchKernelGGL((lstm2_fused<false>), dim3(NBLK), dim3(BDIM), 0, stream,
                       x, xb, Wih0, Whh0, bih0, bhh0, Wih1, Whh1, bih1, bhh1,
                       ring, h1buf, h1f, bar);
  }
  hipLaunchKernelGGL(dense_out, dim3(250), dim3(256), 0, stream, h1f, Wd, bd,
                     (float*)d_out);
}